// Round 2
// baseline (3127.146 us; speedup 1.0000x reference)
//
#include <hip/hip_runtime.h>
#include <hip/hip_bf16.h>

typedef __hip_bfloat16 bf16;
typedef __attribute__((ext_vector_type(8))) short s16x8;
typedef __attribute__((ext_vector_type(4))) short s16x4;
typedef __attribute__((ext_vector_type(4))) float f32x4;

#define NEG_INF (-__builtin_inff())

union V8 { s16x8 v8; s16x4 v4[2]; };

__device__ inline s16x8 ldfrag(const bf16* p) {
    V8 f;
    f.v4[0] = *(const s16x4*)p;
    f.v4[1] = *(const s16x4*)(p + 4);
    return f.v8;
}

__device__ inline unsigned short f2bu(float f) {
    union { bf16 b; unsigned short u; } c;
    c.b = __float2bfloat16(f);
    return c.u;
}

// ---------------------------------------------------------------- dtype sniff
// flag=1 if float inputs are fp32 (low halves of fp32 words look like huge bf16s),
// flag=0 if they are genuine bf16 (all values ~N(0,0.02), no exponent >= 127).
__global__ void sniff_kernel(const unsigned short* __restrict__ tok, int* __restrict__ flag)
{
    int big = 0;
    for (int i = threadIdx.x; i < 2048; i += 64) {
        unsigned e = (tok[i] >> 7) & 0xFFu;
        if (e >= 127u) big++;
    }
    #pragma unroll
    for (int off = 32; off; off >>= 1) big += __shfl_down(big, off);
    if (threadIdx.x == 0) *flag = (big > 64) ? 1 : 0;
}

// ---------------------------------------------------------------- embed
__global__ __launch_bounds__(256) void embed_kernel(
    const int* __restrict__ x, const void* __restrict__ tok,
    const void* __restrict__ pos, float* __restrict__ h,
    const int* __restrict__ flag)
{
    const int f32 = *flag;
    int row = blockIdx.x;           // b*1024 + t
    int t = row & 1023;
    int id = x[row];
    float* hp = h + (long)row * 1024;
    if (f32) {
        const float* tp = (const float*)tok + (long)id * 1024;
        const float* pp = (const float*)pos + (long)t * 1024;
        for (int c = threadIdx.x; c < 1024; c += 256)
            hp[c] = tp[c] + pp[c];
    } else {
        const bf16* tp = (const bf16*)tok + (long)id * 1024;
        const bf16* pp = (const bf16*)pos + (long)t * 1024;
        for (int c = threadIdx.x; c < 1024; c += 256)
            hp[c] = __bfloat162float(tp[c]) + __bfloat162float(pp[c]);
    }
}

// ---------------------------------------------------------------- layernorm
__global__ __launch_bounds__(256) void ln_kernel(
    const float* __restrict__ h, const void* __restrict__ g,
    const void* __restrict__ b, bf16* __restrict__ out,
    const int* __restrict__ flag)
{
    __shared__ float red[8];
    const int f32 = *flag;
    int row = blockIdx.x;
    const float* hp = h + (long)row * 1024;
    int t = threadIdx.x;
    float4 xv = ((const float4*)hp)[t];
    float s  = xv.x + xv.y + xv.z + xv.w;
    float ss = xv.x*xv.x + xv.y*xv.y + xv.z*xv.z + xv.w*xv.w;
    #pragma unroll
    for (int off = 32; off; off >>= 1) {
        s  += __shfl_down(s, off);
        ss += __shfl_down(ss, off);
    }
    int wv = t >> 6, lane = t & 63;
    if (lane == 0) { red[wv] = s; red[4 + wv] = ss; }
    __syncthreads();
    float fs  = red[0] + red[1] + red[2] + red[3];
    float fss = red[4] + red[5] + red[6] + red[7];
    float mu  = fs * (1.0f / 1024.0f);
    float var = fss * (1.0f / 1024.0f) - mu * mu;
    float rstd = rsqrtf(fmaxf(var, 0.f) + 1e-5f);
    bf16* op = out + (long)row * 1024;
    #pragma unroll
    for (int i = 0; i < 4; i++) {
        int c = t * 4 + i;
        float gv, bv_;
        if (f32) { gv = ((const float*)g)[c]; bv_ = ((const float*)b)[c]; }
        else     { gv = __bfloat162float(((const bf16*)g)[c]); bv_ = __bfloat162float(((const bf16*)b)[c]); }
        float xn = (((const float*)&xv)[i] - mu) * rstd;
        op[c] = __float2bfloat16(xn * gv + bv_);
    }
}

// ---------------------------------------------------------------- generic GEMM
// C[M,N](+batch) = A[M,K] @ B[K,N] + bias.  A row-major bf16 (always our ws),
// B row-major bf16 OR fp32 (runtime flag). Tile 64x64, BK=32, 4 waves.
template<bool RELU, bool RES_ADD, bool DYN_OUT>
__global__ __launch_bounds__(256) void gemm_kernel(
    const bf16* __restrict__ A, int lda, long a_bs,
    const void* __restrict__ B, int ldb, long b_bs,
    const void* __restrict__ bias, int bias_bs,
    void* __restrict__ Cv, int ldc, long c_bs, int K,
    const int* __restrict__ flag)
{
    __shared__ bf16 As[64][36];
    __shared__ bf16 Bs[64][36];   // stored transposed: Bs[n][k]
    const int f32 = *flag;
    const int tid = threadIdx.x;
    const int z = blockIdx.z;
    const bf16*  Ab   = A + (long)z * a_bs + (long)blockIdx.x * 64 * lda;
    const bf16*  Bb16 = (const bf16*)B  + (long)z * b_bs + (long)blockIdx.y * 64;
    const float* Bb32 = (const float*)B + (long)z * b_bs + (long)blockIdx.y * 64;
    const int wv = tid >> 6, lane = tid & 63, l16 = lane & 15, quad = lane >> 4;

    f32x4 acc[4];
    #pragma unroll
    for (int s = 0; s < 4; s++) { f32x4 z4 = {0.f,0.f,0.f,0.f}; acc[s] = z4; }

    const bool doA = tid < 128;
    const int ht = tid & 127;
    const int arow = ht >> 1;            // 0..63
    const int ak   = (ht & 1) * 16;      // 0 or 16
    const int bn   = (ht & 7) * 8;       // 0..56
    const int kp   = (ht >> 3) * 2;      // 0..30 (even)

    for (int k0 = 0; k0 < K; k0 += 32) {
        if (doA) {
            const bf16* src = Ab + (long)arow * lda + k0 + ak;
            V8 t0, t1;
            t0.v8 = *(const s16x8*)src;
            t1.v8 = *(const s16x8*)(src + 8);
            *(s16x4*)&As[arow][ak]      = t0.v4[0];
            *(s16x4*)&As[arow][ak + 4]  = t0.v4[1];
            *(s16x4*)&As[arow][ak + 8]  = t1.v4[0];
            *(s16x4*)&As[arow][ak + 12] = t1.v4[1];
        } else if (!f32) {
            const bf16* src = Bb16 + (long)(k0 + kp) * ldb + bn;
            s16x8 r0 = *(const s16x8*)src;
            s16x8 r1 = *(const s16x8*)(src + ldb);
            #pragma unroll
            for (int j = 0; j < 8; ++j) {
                unsigned int lo = (unsigned short)r0[j];
                unsigned int hi = (unsigned short)r1[j];
                *(unsigned int*)&Bs[bn + j][kp] = lo | (hi << 16);
            }
        } else {
            const float* src = Bb32 + (long)(k0 + kp) * ldb + bn;
            float4 a0 = *(const float4*)src;
            float4 a1 = *(const float4*)(src + 4);
            float4 c0 = *(const float4*)(src + ldb);
            float4 c1 = *(const float4*)(src + ldb + 4);
            float av[8] = {a0.x,a0.y,a0.z,a0.w,a1.x,a1.y,a1.z,a1.w};
            float cw[8] = {c0.x,c0.y,c0.z,c0.w,c1.x,c1.y,c1.z,c1.w};
            #pragma unroll
            for (int j = 0; j < 8; ++j) {
                unsigned int lo = f2bu(av[j]);
                unsigned int hi = f2bu(cw[j]);
                *(unsigned int*)&Bs[bn + j][kp] = lo | (hi << 16);
            }
        }
        __syncthreads();
        s16x8 af = ldfrag(&As[wv * 16 + l16][quad * 8]);
        #pragma unroll
        for (int s = 0; s < 4; ++s) {
            s16x8 bfr = ldfrag(&Bs[s * 16 + l16][quad * 8]);
            acc[s] = __builtin_amdgcn_mfma_f32_16x16x32_bf16(af, bfr, acc[s], 0, 0, 0);
        }
        __syncthreads();
    }

    // epilogue: C/D layout col = lane&15, row = quad*4 + reg
    const int gr0 = blockIdx.x * 64 + wv * 16 + quad * 4;
    const int gc0 = blockIdx.y * 64 + l16;
    #pragma unroll
    for (int s = 0; s < 4; ++s) {
        int gc = gc0 + s * 16;
        long bidx = (long)z * bias_bs + gc;
        float bv_ = f32 ? ((const float*)bias)[bidx]
                        : __bfloat162float(((const bf16*)bias)[bidx]);
        #pragma unroll
        for (int r = 0; r < 4; ++r) {
            long idx = (long)(gr0 + r) * ldc + gc;
            if (RES_ADD) {
                float* C = (float*)Cv + (long)z * c_bs;
                C[idx] += acc[s][r] + bv_;
            } else {
                float val = acc[s][r] + bv_;
                if (RELU) val = fmaxf(val, 0.f);
                if (DYN_OUT && f32)
                    ((float*)Cv)[(long)z * c_bs + idx] = val;
                else
                    ((bf16*)Cv)[(long)z * c_bs + idx] = __float2bfloat16(val);
            }
        }
    }
}

// ---------------------------------------------------------------- flash attention
// q,k,v,y: [H][B*T][64]; per-(h,b) base = blockIdx.z * 65536 (z = h*4+b).
__global__ __launch_bounds__(256) void flash_kernel(
    const bf16* __restrict__ q, const bf16* __restrict__ k,
    const bf16* __restrict__ v, bf16* __restrict__ y)
{
    __shared__ bf16 Qs[64][72];
    __shared__ bf16 Ks[64][72];
    __shared__ bf16 Vt[64][72];      // transposed: Vt[vdim][s]
    __shared__ bf16 Ps[4][16][72];   // per-wave P round-trip

    const int tid = threadIdx.x;
    const int wv = tid >> 6, lane = tid & 63, l16 = lane & 15, quad = lane >> 4;
    const long base = (long)blockIdx.z * 65536;
    const int q0 = blockIdx.x * 64;

    {
        int row = tid >> 2, c0 = (tid & 3) * 16;
        const bf16* src = q + base + (long)(q0 + row) * 64 + c0;
        *(s16x8*)&Qs[row][c0]     = *(const s16x8*)src;
        *(s16x8*)&Qs[row][c0 + 8] = *(const s16x8*)(src + 8);
    }
    __syncthreads();
    s16x8 qa0 = *(const s16x8*)&Qs[wv * 16 + l16][quad * 8];
    s16x8 qa1 = *(const s16x8*)&Qs[wv * 16 + l16][32 + quad * 8];

    float m_i[4] = {NEG_INF, NEG_INF, NEG_INF, NEG_INF};
    float l_i[4] = {0.f, 0.f, 0.f, 0.f};
    f32x4 o[4];
    #pragma unroll
    for (int s = 0; s < 4; s++) { f32x4 z4 = {0.f,0.f,0.f,0.f}; o[s] = z4; }
    const int qrow_w = q0 + wv * 16 + quad * 4;

    const int nst = blockIdx.x + 1;
    for (int st = 0; st < nst; ++st) {
        const int s0 = st * 64;
        __syncthreads();
        {
            int row = tid >> 2, c0 = (tid & 3) * 16;
            const bf16* src = k + base + (long)(s0 + row) * 64 + c0;
            *(s16x8*)&Ks[row][c0]     = *(const s16x8*)src;
            *(s16x8*)&Ks[row][c0 + 8] = *(const s16x8*)(src + 8);
            int c0v = (tid & 7) * 8, sp = (tid >> 3) * 2;
            const bf16* vsrc = v + base + (long)(s0 + sp) * 64 + c0v;
            s16x8 vlo = *(const s16x8*)vsrc;
            s16x8 vhi = *(const s16x8*)(vsrc + 64);
            #pragma unroll
            for (int j = 0; j < 8; ++j) {
                unsigned int lo = (unsigned short)vlo[j];
                unsigned int hi = (unsigned short)vhi[j];
                *(unsigned int*)&Vt[c0v + j][sp] = lo | (hi << 16);
            }
        }
        __syncthreads();

        f32x4 S[4];
        #pragma unroll
        for (int s = 0; s < 4; ++s) {
            f32x4 z4 = {0.f,0.f,0.f,0.f};
            s16x8 kb0 = *(const s16x8*)&Ks[s * 16 + l16][quad * 8];
            s16x8 kb1 = *(const s16x8*)&Ks[s * 16 + l16][32 + quad * 8];
            z4 = __builtin_amdgcn_mfma_f32_16x16x32_bf16(qa0, kb0, z4, 0, 0, 0);
            z4 = __builtin_amdgcn_mfma_f32_16x16x32_bf16(qa1, kb1, z4, 0, 0, 0);
            S[s] = z4;
        }
        #pragma unroll
        for (int s = 0; s < 4; ++s) {
            int sg = s0 + s * 16 + l16;
            #pragma unroll
            for (int r = 0; r < 4; ++r) {
                float val = S[s][r] * 0.125f;
                if (sg > qrow_w + r) val = NEG_INF;
                S[s][r] = val;
            }
        }
        float alpha[4];
        #pragma unroll
        for (int r = 0; r < 4; ++r) {
            float mx = fmaxf(fmaxf(S[0][r], S[1][r]), fmaxf(S[2][r], S[3][r]));
            #pragma unroll
            for (int off = 1; off < 16; off <<= 1)
                mx = fmaxf(mx, __shfl_xor(mx, off));
            float mnew = fmaxf(m_i[r], mx);
            alpha[r] = __expf(fmaxf(m_i[r] - mnew, -80.f));
            m_i[r] = mnew;
        }
        float rs[4] = {0.f, 0.f, 0.f, 0.f};
        #pragma unroll
        for (int s = 0; s < 4; ++s)
            #pragma unroll
            for (int r = 0; r < 4; ++r) {
                float p = __expf(fmaxf(S[s][r] - m_i[r], -80.f));
                S[s][r] = p;
                rs[r] += p;
            }
        #pragma unroll
        for (int r = 0; r < 4; ++r) {
            #pragma unroll
            for (int off = 1; off < 16; off <<= 1)
                rs[r] += __shfl_xor(rs[r], off);
            l_i[r] = l_i[r] * alpha[r] + rs[r];
        }
        #pragma unroll
        for (int s = 0; s < 4; ++s)
            #pragma unroll
            for (int r = 0; r < 4; ++r)
                Ps[wv][quad * 4 + r][s * 16 + l16] = __float2bfloat16(S[s][r]);
        __syncthreads();   // defensive: order Ps stores before vector reload
        s16x8 pa0 = *(const s16x8*)&Ps[wv][l16][quad * 8];
        s16x8 pa1 = *(const s16x8*)&Ps[wv][l16][32 + quad * 8];
        #pragma unroll
        for (int s = 0; s < 4; ++s) {
            #pragma unroll
            for (int r = 0; r < 4; ++r) o[s][r] *= alpha[r];
            s16x8 vb0 = *(const s16x8*)&Vt[s * 16 + l16][quad * 8];
            s16x8 vb1 = *(const s16x8*)&Vt[s * 16 + l16][32 + quad * 8];
            o[s] = __builtin_amdgcn_mfma_f32_16x16x32_bf16(pa0, vb0, o[s], 0, 0, 0);
            o[s] = __builtin_amdgcn_mfma_f32_16x16x32_bf16(pa1, vb1, o[s], 0, 0, 0);
        }
    }
    float inv[4];
    #pragma unroll
    for (int r = 0; r < 4; ++r) inv[r] = 1.0f / l_i[r];
    bf16* yp = y + base;
    #pragma unroll
    for (int s = 0; s < 4; ++s)
        #pragma unroll
        for (int r = 0; r < 4; ++r)
            yp[(long)(qrow_w + r) * 64 + s * 16 + l16] = __float2bfloat16(o[s][r] * inv[r]);
}

// ---------------------------------------------------------------- launch
extern "C" void kernel_launch(void* const* d_in, const int* in_sizes, int n_in,
                              void* d_out, int out_size, void* d_ws, size_t ws_size,
                              hipStream_t stream)
{
    const int*  x    = (const int*)d_in[0];
    const void* tok  = d_in[1];
    const void* pos  = d_in[2];
    const void* Wq   = d_in[3];
    const void* bq   = d_in[4];
    const void* Wk   = d_in[5];
    const void* bk_  = d_in[6];
    const void* Wv   = d_in[7];
    const void* bv   = d_in[8];
    const void* Wo   = d_in[9];
    const void* bo   = d_in[10];
    const void* W1   = d_in[11];
    const void* b1   = d_in[12];
    const void* W2   = d_in[13];
    const void* b2   = d_in[14];
    const void* ln1g = d_in[15];
    const void* ln1b = d_in[16];
    const void* ln2g = d_in[17];
    const void* ln2b = d_in[18];
    const void* lnfg = d_in[19];
    const void* lnfb = d_in[20];
    const void* Wout = d_in[21];
    const void* bout = d_in[22];

    char* w = (char*)d_ws;
    int* flagp = (int*)w;   w += 256;
    float* h  = (float*)w;  w += 4096L * 1024 * 4;   // residual stream fp32
    bf16* xn  = (bf16*)w;   w += 4096L * 1024 * 2;   // LN output (reused)
    bf16* qb  = (bf16*)w;   w += 16L * 4096 * 64 * 2;
    bf16* kb  = (bf16*)w;   w += 16L * 4096 * 64 * 2;
    bf16* vb_ = (bf16*)w;   w += 16L * 4096 * 64 * 2;
    bf16* yb  = (bf16*)w;   w += 16L * 4096 * 64 * 2;
    bf16* mid = (bf16*)w;   w += 4096L * 4096 * 2;   // FF intermediate

    sniff_kernel<<<1, 64, 0, stream>>>((const unsigned short*)tok, flagp);
    embed_kernel<<<4096, 256, 0, stream>>>(x, tok, pos, h, flagp);

    for (int layer = 0; layer < 4; ++layer) {
        ln_kernel<<<4096, 256, 0, stream>>>(h, ln1g, ln1b, xn, flagp);
        gemm_kernel<false,false,false><<<dim3(64,1,16), 256, 0, stream>>>(
            xn, 1024, 0, Wq, 64, 65536, bq, 64, qb, 64, 262144, 1024, flagp);
        gemm_kernel<false,false,false><<<dim3(64,1,16), 256, 0, stream>>>(
            xn, 1024, 0, Wk, 64, 65536, bk_, 64, kb, 64, 262144, 1024, flagp);
        gemm_kernel<false,false,false><<<dim3(64,1,16), 256, 0, stream>>>(
            xn, 1024, 0, Wv, 64, 65536, bv, 64, vb_, 64, 262144, 1024, flagp);
        flash_kernel<<<dim3(16,1,64), 256, 0, stream>>>(qb, kb, vb_, yb);
        gemm_kernel<false,true,false><<<dim3(64,1,16), 256, 0, stream>>>(
            yb, 64, 262144, Wo, 64, 4096, bo, 64, h, 1024, 64, 64, flagp);
        ln_kernel<<<4096, 256, 0, stream>>>(h, ln2g, ln2b, xn, flagp);
        gemm_kernel<true,false,false><<<dim3(64,64,1), 256, 0, stream>>>(
            xn, 1024, 0, W1, 4096, 0, b1, 0, mid, 4096, 0, 1024, flagp);
        gemm_kernel<false,true,false><<<dim3(64,16,1), 256, 0, stream>>>(
            mid, 4096, 0, W2, 1024, 0, b2, 0, h, 1024, 0, 4096, flagp);
    }

    ln_kernel<<<4096, 256, 0, stream>>>(h, lnfg, lnfb, xn, flagp);
    gemm_kernel<false,false,true><<<dim3(64,500,1), 256, 0, stream>>>(
        xn, 1024, 0, Wout, 32000, 0, bout, 0, d_out, 32000, 0, 1024, flagp);
}